// Round 1
// baseline (2889.708 us; speedup 1.0000x reference)
//
#include <hip/hip_runtime.h>
#include <math.h>

#define CK_A (-0.75f)

__device__ __forceinline__ float cubicw(float t){
  float at = fabsf(t);
  float at2 = at*at, at3 = at2*at;
  if (at <= 1.f) return (CK_A+2.f)*at3 - (CK_A+3.f)*at2 + 1.f;
  if (at < 2.f)  return CK_A*at3 - 5.f*CK_A*at2 + 8.f*CK_A*at - 4.f*CK_A;
  return 0.f;
}

// ---------------- conv 3x3 SAME + bias + relu ----------------
// in:  base + b*inBStride + ci*H*W
// out: base + b*outBStride + co*H*W
__global__ __launch_bounds__(256) void conv3x3_relu(
    const float* __restrict__ in, const float* __restrict__ w, const float* __restrict__ bias,
    float* __restrict__ out, int CI, int H, int W, long inBStride, long outBStride)
{
  const int TS = 16;
  int tilesX = (W + TS - 1)/TS;
  int tx0 = (blockIdx.x % tilesX)*TS;
  int ty0 = (blockIdx.x / tilesX)*TS;
  int co = blockIdx.y, b = blockIdx.z;
  int lx = threadIdx.x & 15, ly = threadIdx.x >> 4;
  __shared__ float tile[18][20];
  const float* inb = in + (long)b*inBStride;
  const float* wp = w + (long)co*CI*9;
  int ox = tx0+lx, oy = ty0+ly;
  float acc = 0.f;
  for (int ci=0; ci<CI; ci++){
    const float* ic = inb + (long)ci*H*W;
    for (int idx = threadIdx.x; idx < 18*18; idx += 256){
      int r = idx/18, c = idx - r*18;
      int gy = ty0 + r - 1, gx = tx0 + c - 1;
      tile[r][c] = (gy>=0 && gy<H && gx>=0 && gx<W) ? ic[gy*W+gx] : 0.f;
    }
    __syncthreads();
    const float* wc = wp + ci*9;
    float w0=wc[0],w1=wc[1],w2=wc[2],w3=wc[3],w4=wc[4],w5=wc[5],w6=wc[6],w7=wc[7],w8=wc[8];
    acc = fmaf(tile[ly+0][lx+0], w0, acc);
    acc = fmaf(tile[ly+0][lx+1], w1, acc);
    acc = fmaf(tile[ly+0][lx+2], w2, acc);
    acc = fmaf(tile[ly+1][lx+0], w3, acc);
    acc = fmaf(tile[ly+1][lx+1], w4, acc);
    acc = fmaf(tile[ly+1][lx+2], w5, acc);
    acc = fmaf(tile[ly+2][lx+0], w6, acc);
    acc = fmaf(tile[ly+2][lx+1], w7, acc);
    acc = fmaf(tile[ly+2][lx+2], w8, acc);
    __syncthreads();
  }
  if (ox < W && oy < H){
    float r = acc + bias[co];
    out[(long)b*outBStride + (long)co*H*W + (long)oy*W + ox] = fmaxf(r, 0.f);
  }
}

// ---------------- maxpool 2x2 stride 2 ----------------
__global__ void maxpool2(const float* __restrict__ in, float* __restrict__ out, long NC, int Hi, int Wi){
  int Ho = Hi>>1, Wo = Wi>>1;
  long total = NC * Ho * Wo;
  long idx = (long)blockIdx.x*256 + threadIdx.x;
  if (idx >= total) return;
  int x = (int)(idx % Wo); long t = idx / Wo; int y = (int)(t % Ho); long nc = t / Ho;
  const float* p = in + (nc*Hi + 2*y)*(long)Wi + 2*x;
  float v = fmaxf(fmaxf(p[0], p[1]), fmaxf(p[Wi], p[Wi+1]));
  out[idx] = v;
}

// ---------------- bicubic upsample (align_corners=True) ----------------
__global__ __launch_bounds__(256) void bicubic_up(
    const float* __restrict__ in, float* __restrict__ out,
    int Hin, int Win, int Hout, int Wout, long inBStride, long outBStride)
{
  int c = blockIdx.x, b = blockIdx.y;
  __shared__ float s[576];
  const float* ip = in + (long)b*inBStride + (long)c*Hin*Win;
  float* op = out + (long)b*outBStride + (long)c*Hout*Wout;
  int n = Hin*Win;
  for (int i = threadIdx.x; i < n; i += 256) s[i] = ip[i];
  __syncthreads();
  float scy = (float)((double)(Hin-1)/(double)(Hout-1));
  float scx = (float)((double)(Win-1)/(double)(Wout-1));
  int total = Hout*Wout;
  for (int idx = threadIdx.x; idx < total; idx += 256){
    int ox = idx % Wout, oy = idx / Wout;
    float py = oy * scy, px = ox * scx;
    float iy0f = floorf(py), ix0f = floorf(px);
    int iy0 = (int)iy0f, ix0 = (int)ix0f;
    float fy = py - iy0f, fx = px - ix0f;
    float wy[4], wx[4]; int xs[4], ys[4];
    #pragma unroll
    for (int t=0;t<4;t++){
      wy[t] = cubicw(fy - (float)(t-1));
      wx[t] = cubicw(fx - (float)(t-1));
      ys[t] = min(max(iy0 + t - 1, 0), Hin-1);
      xs[t] = min(max(ix0 + t - 1, 0), Win-1);
    }
    float acc = 0.f;
    #pragma unroll
    for (int i=0;i<4;i++){
      const float* row = &s[ys[i]*Win];
      float rs = wx[0]*row[xs[0]] + wx[1]*row[xs[1]] + wx[2]*row[xs[2]] + wx[3]*row[xs[3]];
      acc = fmaf(wy[i], rs, acc);
    }
    op[idx] = acc;
  }
}

// ---------------- normalizer ----------------
__global__ __launch_bounds__(256) void mean_k(const float* __restrict__ fR, const float* __restrict__ fT, float* __restrict__ mean){
  int c = blockIdx.x % 320, b = blockIdx.x / 320;
  const float* a = fR + ((long)b*320+c)*9216L;
  const float* t = fT + ((long)b*320+c)*2304L;
  float s = 0.f;
  for (int i=threadIdx.x;i<9216;i+=256) s += a[i];
  for (int i=threadIdx.x;i<2304;i+=256) s += t[i];
  __shared__ float sm[4];
  for (int o=32;o;o>>=1) s += __shfl_down(s,o);
  int lane = threadIdx.x & 63, wv = threadIdx.x >> 6;
  if (lane==0) sm[wv] = s;
  __syncthreads();
  if (threadIdx.x==0) mean[b*320+c] = (sm[0]+sm[1]+sm[2]+sm[3]) * (1.f/11520.f);
}

__global__ void norm_apply(float* __restrict__ f, const float* __restrict__ mean, long perChan, long total){
  long idx = (long)blockIdx.x*256 + threadIdx.x;
  if (idx >= total) return;
  long c = (idx / perChan) % 320;
  long b = idx / (perChan*320);
  float m = mean[b*320+c];
  f[idx] = (f[idx] - m) / (m + 1e-8f);
}

// ---------------- dist GEMM: D[m][n] = sum_k A[k][m]*B[k][n] ----------------
// A: [320][9216] (one batch), B: [320][2304], D: [9216][2304]
__global__ __launch_bounds__(256) void gemm128(const float* __restrict__ A, const float* __restrict__ Bv, float* __restrict__ D){
  const int M=9216, N=2304, K=320;
  int n0 = blockIdx.x*128, m0 = blockIdx.y*128;
  const float* Ab = A + m0;
  const float* Bb = Bv + n0;
  __shared__ float As[8][128], Bs[8][128];
  int tid = threadIdx.x;
  int tn = tid & 15, tm = tid >> 4;
  float acc[8][8];
  #pragma unroll
  for (int i=0;i<8;i++)
    #pragma unroll
    for (int j=0;j<8;j++) acc[i][j]=0.f;
  int la = tid*4; int lk = la >> 7; int lm = la & 127;
  for (int k0=0;k0<K;k0+=8){
    *(float4*)&As[lk][lm] = *(const float4*)&Ab[(long)(k0+lk)*M + lm];
    *(float4*)&Bs[lk][lm] = *(const float4*)&Bb[(long)(k0+lk)*N + lm];
    __syncthreads();
    #pragma unroll
    for (int kk=0;kk<8;kk++){
      float4 a0 = *(float4*)&As[kk][tm*4];
      float4 a1 = *(float4*)&As[kk][64+tm*4];
      float4 b0 = *(float4*)&Bs[kk][tn*4];
      float4 b1 = *(float4*)&Bs[kk][64+tn*4];
      float av[8]={a0.x,a0.y,a0.z,a0.w,a1.x,a1.y,a1.z,a1.w};
      float bw[8]={b0.x,b0.y,b0.z,b0.w,b1.x,b1.y,b1.z,b1.w};
      #pragma unroll
      for (int i=0;i<8;i++)
        #pragma unroll
        for (int j=0;j<8;j++) acc[i][j] = fmaf(av[i], bw[j], acc[i][j]);
    }
    __syncthreads();
  }
  float* Db = D + (long)m0*N + n0;
  #pragma unroll
  for (int i=0;i<8;i++){
    int mr = (i<4) ? (tm*4+i) : (64+tm*4+(i-4));
    float4 o0 = make_float4(acc[i][0],acc[i][1],acc[i][2],acc[i][3]);
    float4 o1 = make_float4(acc[i][4],acc[i][5],acc[i][6],acc[i][7]);
    *(float4*)&Db[(long)mr*N + tn*4] = o0;
    *(float4*)&Db[(long)mr*N + 64 + tn*4] = o1;
  }
}

// ---------------- row softmax stats (axis=-1, coef_tmp) ----------------
__global__ __launch_bounds__(256) void row_stats(const float* __restrict__ D, const float* __restrict__ coeft,
                                                 float* __restrict__ rmax, float* __restrict__ rsum){
  int m = blockIdx.x;
  const float* drow = D + (long)m*2304;
  float ct = *coeft;
  float v[9];
  float mx = -INFINITY;
  #pragma unroll
  for (int i=0;i<9;i++){ v[i] = ct * drow[threadIdx.x + i*256]; mx = fmaxf(mx, v[i]); }
  __shared__ float sm[4];
  for (int o=32;o;o>>=1) mx = fmaxf(mx, __shfl_down(mx,o));
  int lane = threadIdx.x & 63, wv = threadIdx.x>>6;
  if (lane==0) sm[wv]=mx;
  __syncthreads();
  mx = fmaxf(fmaxf(sm[0],sm[1]),fmaxf(sm[2],sm[3]));
  __syncthreads();
  float s=0.f;
  #pragma unroll
  for (int i=0;i<9;i++) s += expf(v[i]-mx);
  for (int o=32;o;o>>=1) s += __shfl_down(s,o);
  if (lane==0) sm[wv]=s;
  __syncthreads();
  if (threadIdx.x==0){ rmax[m]=mx; rsum[m]=sm[0]+sm[1]+sm[2]+sm[3]; }
}

// ---------------- column softmax stats (axis=-2, coef_ref) ----------------
__device__ __forceinline__ void merge_ms(float& m, float& s, float m2, float s2){
  float M = fmaxf(m, m2);
  s = s*expf(m - M) + s2*expf(m2 - M);
  m = M;
}

__global__ __launch_bounds__(256) void colstat_part(const float* __restrict__ D, const float* __restrict__ coefr,
                                                    float* __restrict__ pm, float* __restrict__ ps){
  int tx = threadIdx.x & 63, ty = threadIdx.x >> 6;
  int n = blockIdx.x*64 + tx;
  float cr = *coefr;
  float m = -INFINITY, s = 0.f;
  int r0 = blockIdx.y * 576;
  for (int r = r0 + ty; r < r0 + 576; r += 4){
    float v = cr * D[(long)r*2304 + n];
    if (v > m){ s = s*expf(m - v) + 1.f; m = v; }
    else s += expf(v - m);
  }
  __shared__ float smm[4][64], sms[4][64];
  smm[ty][tx]=m; sms[ty][tx]=s;
  __syncthreads();
  if (ty==0){
    #pragma unroll
    for (int k=1;k<4;k++) merge_ms(m, s, smm[k][tx], sms[k][tx]);
    pm[(long)blockIdx.y*2304 + n] = m;
    ps[(long)blockIdx.y*2304 + n] = s;
  }
}

__global__ void colstat_merge(const float* __restrict__ pm, const float* __restrict__ ps,
                              float* __restrict__ cm, float* __restrict__ cs){
  int idx = blockIdx.x*256 + threadIdx.x;
  if (idx >= 2304) return;
  float m=-INFINITY, s=0.f;
  for (int k=0;k<16;k++){
    merge_ms(m, s, pm[(long)k*2304+idx], ps[(long)k*2304+idx]);
  }
  cm[idx]=m; cs[idx]=s;
}

// ---------------- confidence + top-10 mean ----------------
__global__ __launch_bounds__(256) void conf_topk(const float* __restrict__ D,
    const float* __restrict__ coefr, const float* __restrict__ coeft,
    const float* __restrict__ rmax, const float* __restrict__ rsum,
    const float* __restrict__ cmax, const float* __restrict__ csum,
    float* __restrict__ outp){
  int m = blockIdx.x;
  const float* drow = D + (long)m*2304;
  float cr = *coefr, ct = *coeft;
  float rm = rmax[m], rs = rsum[m];
  float vals[9];
  #pragma unroll
  for (int i=0;i<9;i++){
    int n = threadIdx.x + i*256;
    float d = drow[n];
    float e = expf(0.5f*((cr+ct)*d - cmax[n] - rm));
    vals[i] = e / sqrtf(csum[n]*rs);
  }
  __shared__ float smv[4]; __shared__ int smi[4];
  float total = 0.f;
  for (int t=0;t<10;t++){
    float lv = -1.f; int li = 0;
    #pragma unroll
    for (int i=0;i<9;i++) if (vals[i] > lv){ lv = vals[i]; li = i; }
    float v = lv; int idx = li*256 + threadIdx.x;
    for (int o=32;o;o>>=1){
      float v2 = __shfl_down(v,o); int i2 = __shfl_down(idx,o);
      if (v2 > v || (v2 == v && i2 < idx)){ v=v2; idx=i2; }
    }
    int lane = threadIdx.x&63, wv = threadIdx.x>>6;
    if (lane==0){ smv[wv]=v; smi[wv]=idx; }
    __syncthreads();
    float bv = smv[0]; int bi = smi[0];
    #pragma unroll
    for (int k=1;k<4;k++){ float v2=smv[k]; int i2=smi[k]; if (v2>bv || (v2==bv && i2<bi)){bv=v2;bi=i2;} }
    total += bv;
    if ((bi & 255) == threadIdx.x) vals[bi>>8] = -2.f;
    __syncthreads();
  }
  if (threadIdx.x==0) outp[m] = total*0.1f;
}

// ---------------- host ----------------
extern "C" void kernel_launch(void* const* d_in, const int* in_sizes, int n_in,
                              void* d_out, int out_size, void* d_ws, size_t ws_size,
                              hipStream_t stream) {
  const float *W[8], *Bp[8], *xr, *xt, *cr, *ct;
  if (in_sizes[0] == 1728){
    for (int i=0;i<8;i++){ W[i]=(const float*)d_in[2*i]; Bp[i]=(const float*)d_in[2*i+1]; }
    xr=(const float*)d_in[16]; xt=(const float*)d_in[17];
    cr=(const float*)d_in[18]; ct=(const float*)d_in[19];
  } else {
    xr=(const float*)d_in[0]; xt=(const float*)d_in[1];
    cr=(const float*)d_in[2]; ct=(const float*)d_in[3];
    for (int i=0;i<8;i++){ W[i]=(const float*)d_in[4+2*i]; Bp[i]=(const float*)d_in[5+2*i]; }
  }

  float* ws = (float*)d_ws;
  long off = 0;
  auto alloc = [&](long nfl){ float* p = ws + off; off += (nfl + 63) & ~63L; return p; };
  float* featR = alloc(2L*320*9216);     // [2,320,96,96]
  float* featT = alloc(2L*320*2304);     // [2,320,48,48]
  float* meanb = alloc(640);
  float* rmax  = alloc(2L*9216);
  float* rsum  = alloc(2L*9216);
  float* pm    = alloc(16L*2304);
  float* ps    = alloc(16L*2304);
  float* cm    = alloc(2304);
  float* cs    = alloc(2304);
  float* scratch = alloc(9216L*2304);    // dist (per batch), aliases conv temps
  if ((size_t)(off*4) > ws_size) return; // insufficient scratch: bail cleanly

  // conv temporaries aliased inside scratch (dead before dist is written)
  float* tA = scratch;                   // [2,64,96,96]
  float* tB = tA + 2L*64*9216;           // [2,64,48,48]
  float* tC = tB + 2L*64*2304;           // [2,128,48,48]
  float* tD = tC + 2L*128*2304;          // [2,128,48,48]
  float* tE = tD + 2L*128*2304;          // [2,128,24,24]
  float* tF = tE + 2L*128*576;           // [2,256,24,24]
  float* tG = tF + 2L*256*576;           // [2,256,24,24]
  float* dist = scratch;

  auto convl = [&](const float* in, int i, float* out, int CI, int CO, int H, int Wd, long inBS, long outBS){
    int tiles = ((Wd+15)/16)*((H+15)/16);
    conv3x3_relu<<<dim3(tiles, CO, 2), 256, 0, stream>>>(in, W[i], Bp[i], out, CI, H, Wd, inBS, outBS);
  };
  auto pooll = [&](const float* in, float* out, long NC, int Hi, int Wi){
    long total = NC*(Hi/2)*(Wi/2);
    maxpool2<<<dim3((unsigned)((total+255)/256)), 256, 0, stream>>>(in, out, NC, Hi, Wi);
  };

  // ---- reference image path (96x96) ----
  convl(xr, 0, featR, 3, 64, 96, 96, 3L*9216, 320L*9216);
  convl(featR, 1, tA, 64, 64, 96, 96, 320L*9216, 64L*9216);
  pooll(tA, tB, 2L*64, 96, 96);
  convl(tB, 2, tC, 64, 128, 48, 48, 64L*2304, 128L*2304);
  convl(tC, 3, tD, 128, 128, 48, 48, 128L*2304, 128L*2304);
  pooll(tD, tE, 2L*128, 48, 48);
  convl(tE, 4, tF, 128, 256, 24, 24, 128L*576, 256L*576);
  convl(tF, 5, tG, 256, 256, 24, 24, 256L*576, 256L*576);
  convl(tG, 6, tF, 256, 256, 24, 24, 256L*576, 256L*576);
  convl(tF, 7, tG, 256, 256, 24, 24, 256L*576, 256L*576);
  bicubic_up<<<dim3(256,2), 256, 0, stream>>>(tG, featR + 64L*9216, 24,24,96,96, 256L*576, 320L*9216);

  // ---- template path (48x48) ----
  convl(xt, 0, featT, 3, 64, 48, 48, 3L*2304, 320L*2304);
  convl(featT, 1, tA, 64, 64, 48, 48, 320L*2304, 64L*2304);
  pooll(tA, tB, 2L*64, 48, 48);
  convl(tB, 2, tC, 64, 128, 24, 24, 64L*576, 128L*576);
  convl(tC, 3, tD, 128, 128, 24, 24, 128L*576, 128L*576);
  pooll(tD, tE, 2L*128, 24, 24);
  convl(tE, 4, tF, 128, 256, 12, 12, 128L*144, 256L*144);
  convl(tF, 5, tG, 256, 256, 12, 12, 256L*144, 256L*144);
  convl(tG, 6, tF, 256, 256, 12, 12, 256L*144, 256L*144);
  convl(tF, 7, tG, 256, 256, 12, 12, 256L*144, 256L*144);
  bicubic_up<<<dim3(256,2), 256, 0, stream>>>(tG, featT + 64L*2304, 12,12,48,48, 256L*144, 320L*2304);

  // ---- normalizer (std = mean bug preserved) ----
  mean_k<<<640, 256, 0, stream>>>(featR, featT, meanb);
  norm_apply<<<dim3((unsigned)((5898240L+255)/256)), 256, 0, stream>>>(featR, meanb, 9216L, 2L*320*9216);
  norm_apply<<<dim3((unsigned)((1474560L+255)/256)), 256, 0, stream>>>(featT, meanb, 2304L, 2L*320*2304);

  // ---- per-batch: dist GEMM, softmax stats, conf + top-10 ----
  for (int b=0; b<2; b++){
    const float* Ab = featR + (long)b*320*9216;
    const float* Bb = featT + (long)b*320*2304;
    gemm128<<<dim3(18,72), 256, 0, stream>>>(Ab, Bb, dist);
    row_stats<<<dim3(9216), 256, 0, stream>>>(dist, ct, rmax + (long)b*9216, rsum + (long)b*9216);
    colstat_part<<<dim3(36,16), 256, 0, stream>>>(dist, cr, pm, ps);
    colstat_merge<<<dim3(9), 256, 0, stream>>>(pm, ps, cm, cs);
    conf_topk<<<dim3(9216), 256, 0, stream>>>(dist, cr, ct,
        rmax + (long)b*9216, rsum + (long)b*9216, cm, cs, (float*)d_out + (long)b*9216);
  }
}